// Round 15
// baseline (222.782 us; speedup 1.0000x reference)
//
#include <hip/hip_runtime.h>

typedef __bf16 bf16x8 __attribute__((ext_vector_type(8)));
typedef float f32x4 __attribute__((ext_vector_type(4)));
typedef short short4v __attribute__((ext_vector_type(4)));
typedef short short8v __attribute__((ext_vector_type(8)));

#define DEVI static __device__ __forceinline__

// fp32 -> bf16 bits via hardware cvt (RTNE; pairs fold to v_cvt_pk_bf16_f32)
DEVI short f2bf(float f) {
    union { __bf16 b; short s; } u;
    u.b = (__bf16)f;
    return u.s;
}

// async global -> LDS, 16B per lane (dest linear: wave-uniform base + lane*16)
DEVI void gld16(const void* g, void* l) {
    __builtin_amdgcn_global_load_lds(
        (const __attribute__((address_space(1))) unsigned int*)g,
        (__attribute__((address_space(3))) unsigned int*)l, 16, 0, 0);
}

// ---------------- x fp32 -> bf16 ----------------
__global__ __launch_bounds__(256) void cvt_x_kernel(const float* __restrict__ x,
                                                    short* __restrict__ xb) {
    int i = (blockIdx.x * 256 + threadIdx.x) * 8;
    f32x4 a = *(const f32x4*)(x + i);
    f32x4 b = *(const f32x4*)(x + i + 4);
    short8v o;
    o[0]=f2bf(a[0]); o[1]=f2bf(a[1]); o[2]=f2bf(a[2]); o[3]=f2bf(a[3]);
    o[4]=f2bf(b[0]); o[5]=f2bf(b[1]); o[6]=f2bf(b[2]); o[7]=f2bf(b[3]);
    *(short8v*)(xb + i) = o;
}

// ------------- weights fp32 -> bf16, fused. z=0,1,2: Wq,Wk,Wv transposed [N][K];
// z=3: Wo PLAIN [K][N] bf16; z=4: W1 transposed.
__global__ __launch_bounds__(256) void wtrans5_kernel(const float* __restrict__ w0,
                                                      const float* __restrict__ w1,
                                                      const float* __restrict__ w2,
                                                      const float* __restrict__ w3,
                                                      const float* __restrict__ w4,
                                                      short* __restrict__ dst) {
    const float* w;
    switch (blockIdx.z) {
        case 0: w = w0; break;
        case 1: w = w1; break;
        case 2: w = w2; break;
        case 3: w = w3; break;
        default: w = w4; break;
    }
    short* wt = dst + (size_t)blockIdx.z * 1048576;
    __shared__ float t[64][68];
    const int tid = threadIdx.x;
    const int k0 = blockIdx.x * 64, n0 = blockIdx.y * 64;
#pragma unroll
    for (int it = 0; it < 4; ++it) {
        int r = (tid >> 4) + it * 16;
        int cc = (tid & 15) * 4;
        f32x4 vv = *(const f32x4*)(w + (k0 + r) * 1024 + n0 + cc);
        *(f32x4*)&t[r][cc] = vv;
    }
    __syncthreads();
    if (blockIdx.z == 3) {
#pragma unroll
        for (int it = 0; it < 4; ++it) {
            int r = (tid >> 4) + it * 16;
            int cc = (tid & 15) * 4;
            short4v o;
            o[0] = f2bf(t[r][cc + 0]);
            o[1] = f2bf(t[r][cc + 1]);
            o[2] = f2bf(t[r][cc + 2]);
            o[3] = f2bf(t[r][cc + 3]);
            *(short4v*)(wt + (k0 + r) * 1024 + n0 + cc) = o;
        }
    } else {
#pragma unroll
        for (int it = 0; it < 4; ++it) {
            int n = (tid >> 4) + it * 16;
            int kc = (tid & 15) * 4;
            short4v o;
            o[0] = f2bf(t[kc + 0][n]);
            o[1] = f2bf(t[kc + 1][n]);
            o[2] = f2bf(t[kc + 2][n]);
            o[3] = f2bf(t[kc + 3][n]);
            *(short4v*)(wt + (n0 + n) * 1024 + k0 + kc) = o;
        }
    }
}

// ------- bcomb[n] = b1[n] + sum_j bo[j]*W1[j][n], parallel: 64 blocks x 16 n -------
__global__ __launch_bounds__(256) void bcomb_kernel(const float* __restrict__ bo,
                                                    const float* __restrict__ W1,
                                                    const float* __restrict__ b1,
                                                    float* __restrict__ out) {
    __shared__ f32x4 red[64][4];
    const int tid = threadIdx.x;
    const int jg = tid >> 2;
    const int nq = tid & 3;
    const int n = blockIdx.x * 16 + nq * 4;
    f32x4 acc = {0.f, 0.f, 0.f, 0.f};
#pragma unroll 4
    for (int jj = 0; jj < 16; ++jj) {
        int j = jg * 16 + jj;
        float s = bo[j];
        f32x4 w = *(const f32x4*)(W1 + j * 1024 + n);
        acc[0] += s * w[0]; acc[1] += s * w[1]; acc[2] += s * w[2]; acc[3] += s * w[3];
    }
    red[jg][nq] = acc;
    __syncthreads();
#pragma unroll
    for (int s = 32; s >= 1; s >>= 1) {
        if (jg < s) {
            f32x4 a = red[jg][nq], b2 = red[jg + s][nq];
            a[0] += b2[0]; a[1] += b2[1]; a[2] += b2[2]; a[3] += b2[3];
            red[jg][nq] = a;
        }
        __syncthreads();
    }
    if (jg == 0) {
        f32x4 r = red[0][nq];
        f32x4 bb = *(const f32x4*)(b1 + n);
        r[0] += bb[0]; r[1] += bb[1]; r[2] += bb[2]; r[3] += bb[3];
        *(f32x4*)(out + n) = r;
    }
}

// ------- 64x64-tile GEMM for the small 1024^3 composite (256 blocks, full chip) -------
__global__ __launch_bounds__(256, 2) void gemm64_bt(const short* __restrict__ A,
                                                    const short* __restrict__ Bt,
                                                    short* __restrict__ outp) {
    __shared__ short As[64 * 64];
    __shared__ short Bs[64 * 64];
    const int tid = threadIdx.x;
    const int lane = tid & 63;
    const int wid = tid >> 6;
    const int g = lane >> 4, c = lane & 15;
    const int wr = wid >> 1, wc = wid & 1;
    const int m0 = blockIdx.x * 64, n0 = blockIdx.y * 64;

    const f32x4 fz = {0.f, 0.f, 0.f, 0.f};
    f32x4 acc[2][2];
#pragma unroll
    for (int m = 0; m < 2; ++m)
#pragma unroll
        for (int n = 0; n < 2; ++n) acc[m][n] = fz;

    for (int kt = 0; kt < 16; ++kt) {
        const int k0 = kt * 64;
        __syncthreads();
#pragma unroll
        for (int st = 0; st < 2; ++st) {
            int ci = st * 256 + tid;
            int r = ci >> 3;
            int cc = ((ci & 7) ^ (r & 7)) << 3;
            gld16(A + (m0 + r) * 1024 + k0 + cc, (char*)As + ci * 16);
            gld16(Bt + (n0 + r) * 1024 + k0 + cc, (char*)Bs + ci * 16);
        }
        __syncthreads();
#pragma unroll
        for (int kk = 0; kk < 2; ++kk) {
            bf16x8 af[2], bfr[2];
#pragma unroll
            for (int m = 0; m < 2; ++m) {
                int row = wr * 32 + m * 16 + c;
                af[m] = *(const bf16x8*)((const char*)As + row * 128 + ((kk * 64 + g * 16) ^ ((row & 7) << 4)));
            }
#pragma unroll
            for (int n = 0; n < 2; ++n) {
                int row = wc * 32 + n * 16 + c;
                bfr[n] = *(const bf16x8*)((const char*)Bs + row * 128 + ((kk * 64 + g * 16) ^ ((row & 7) << 4)));
            }
#pragma unroll
            for (int m = 0; m < 2; ++m)
#pragma unroll
                for (int n = 0; n < 2; ++n)
                    acc[m][n] = __builtin_amdgcn_mfma_f32_16x16x32_bf16(af[m], bfr[n], acc[m][n], 0, 0, 0);
        }
    }

#pragma unroll
    for (int n = 0; n < 2; ++n) {
        const int col = n0 + wc * 32 + n * 16 + c;
#pragma unroll
        for (int m = 0; m < 2; ++m) {
            const int row0 = m0 + wr * 32 + m * 16 + g * 4;
#pragma unroll
            for (int i = 0; i < 4; ++i)
                outp[(row0 + i) * 1024 + col] = f2bf(acc[m][n][i]);
        }
    }
}

// ---------------- GEMM (m97 structure + T2 swizzle + T1 XCD swizzle): C = A @ Bt^T -------
// MODE 0: scatter bf16 to q/k/v; q pre-scaled by 1/8*log2(e)
// MODE 2: fp32 out = relu(acc + bias)
// T1: grid remap so each XCD gets a contiguous chunk of blocks (requires nwg%8==0:
// MODE0 grid 64x24=1536, MODE2 64x8=512 -- both ok).
template<int MODE>
__global__ __launch_bounds__(256, 2) void gemm_bt(const short* __restrict__ A,
                                                  const short* __restrict__ Bt,
                                                  const float* __restrict__ bias,
                                                  void* __restrict__ outp) {
    __shared__ short As[128 * 64];
    __shared__ short Bs[128 * 64];
    const int tid = threadIdx.x;
    const int lane = tid & 63;
    const int wid = tid >> 6;
    const int g = lane >> 4, c = lane & 15;
    const int wr = wid >> 1, wc = wid & 1;

    // T1 XCD-aware block swizzle (bijective since nwg % 8 == 0)
    const int nwg = gridDim.x * gridDim.y;
    const int flat = blockIdx.x + gridDim.x * blockIdx.y;
    const int cpx = nwg >> 3;
    const int swzb = (flat & 7) * cpx + (flat >> 3);
    const int bx = swzb % gridDim.x, by = swzb / gridDim.x;
    const int m0 = bx * 128, n0 = by * 128;

    const f32x4 fz = {0.f, 0.f, 0.f, 0.f};
    f32x4 acc[4][4];
#pragma unroll
    for (int m = 0; m < 4; ++m)
#pragma unroll
        for (int n = 0; n < 4; ++n) acc[m][n] = fz;

    for (int kt = 0; kt < 16; ++kt) {
        const int k0 = kt * 64;
        __syncthreads();
#pragma unroll
        for (int st = 0; st < 4; ++st) {
            int ci = st * 256 + tid;
            int r = ci >> 3;
            int cc = ((ci & 7) ^ (r & 7)) << 3;
            gld16(A + (m0 + r) * 1024 + k0 + cc, (char*)As + ci * 16);
            gld16(Bt + (n0 + r) * 1024 + k0 + cc, (char*)Bs + ci * 16);
        }
        __syncthreads();
#pragma unroll
        for (int kk = 0; kk < 2; ++kk) {
            bf16x8 af[4], bfr[4];
#pragma unroll
            for (int m = 0; m < 4; ++m) {
                int row = wr * 64 + m * 16 + c;
                af[m] = *(const bf16x8*)((const char*)As + row * 128 + ((kk * 64 + g * 16) ^ ((row & 7) << 4)));
            }
#pragma unroll
            for (int n = 0; n < 4; ++n) {
                int row = wc * 64 + n * 16 + c;
                bfr[n] = *(const bf16x8*)((const char*)Bs + row * 128 + ((kk * 64 + g * 16) ^ ((row & 7) << 4)));
            }
#pragma unroll
            for (int m = 0; m < 4; ++m)
#pragma unroll
                for (int n = 0; n < 4; ++n)
                    acc[m][n] = __builtin_amdgcn_mfma_f32_16x16x32_bf16(af[m], bfr[n], acc[m][n], 0, 0, 0);
        }
    }

#pragma unroll
    for (int n = 0; n < 4; ++n) {
        const int col = n0 + wc * 64 + n * 16 + c;
        float bv = 0.f;
        if (MODE == 2) bv = bias[col];
#pragma unroll
        for (int m = 0; m < 4; ++m) {
            const int row0 = m0 + wr * 64 + m * 16 + g * 4;
#pragma unroll
            for (int i = 0; i < 4; ++i) {
                const int row = row0 + i;
                float val = acc[m][n][i];
                if (MODE == 0) {
                    short* qkv = (short*)outp;
                    int which = col >> 10;
                    int hc = col & 1023;
                    if (which == 0) val *= 0.18033688011112042f;
                    int dst = which * 8388608 +
                              (((row >> 10) * 16 + (hc >> 6)) * 1024 + (row & 1023)) * 64 + (hc & 63);
                    qkv[dst] = f2bf(val);
                } else {
                    ((float*)outp)[row * 1024 + col] = fmaxf(val + bv, 0.f);
                }
            }
        }
    }
}

// ---------------- causal flash attention v3.3: round-11 v3.2 per-tile code, UNPAIRED ----------------
// grid (8, B*H) = 1024 blocks, one 128-row q-tile each (qt = blockIdx.x). LDS 48KB ->
// 3 blocks/CU resident (24 waves/CU vs paired 16); the 1024-block pool lets the
// scheduler backfill as short (low-qt) blocks finish. Per-tile machinery identical
// to the round-11 passing kernel.
__global__ __launch_bounds__(512, 2) void attn_kernel(const short* __restrict__ qp,
                                                      const short* __restrict__ kp,
                                                      const short* __restrict__ vp,
                                                      short* __restrict__ ao) {
    __shared__ short Ks[128 * 64];    // row t: 128B rows, swz ((r&7)<<4)
    __shared__ short Vt[64 * 128];    // row d: 256B rows, swz (((d&7)^(d>>3))<<4)
    __shared__ short Ps[8][16 * 64];  // per-wave P half [q][64], 128B rows, swz ((q&7)<<4)
    const int tid = threadIdx.x;
    const int lane = tid & 63;
    const int wid = tid >> 6;
    const int g = lane >> 4, c = lane & 15;
    const int bh = blockIdx.y;
    const int base = bh * 65536;  // 1024*64
    const int b = bh >> 4, h = bh & 15;

    const int r0 = tid >> 3, c0 = (tid & 7) << 3;
    const int r1 = 64 + r0;
    const int vt0 = (tid >> 4) * 4;   // 0..124
    const int vd0 = (tid & 15) * 4;   // 0..60

    const f32x4 fz = {0.f, 0.f, 0.f, 0.f};

    bf16x8 kreg0, kreg1;
    short4v vreg0, vreg1, vreg2, vreg3;

    const int qt = blockIdx.x;
    const int q0 = qt * 128;
    const int nkt = qt + 1;

    const int qrow = q0 + wid * 16 + c;
    bf16x8 qf0 = *(const bf16x8*)(qp + base + qrow * 64 + g * 8);
    bf16x8 qf1 = *(const bf16x8*)(qp + base + qrow * 64 + 32 + g * 8);

    f32x4 accO[4];
#pragma unroll
    for (int n = 0; n < 4; ++n) accO[n] = fz;
    float mrow[4], lsum[4];
#pragma unroll
    for (int i = 0; i < 4; ++i) { mrow[i] = -1e30f; lsum[i] = 0.f; }

    kreg0 = *(const bf16x8*)(kp + base + r0 * 64 + c0);
    kreg1 = *(const bf16x8*)(kp + base + r1 * 64 + c0);
    vreg0 = *(const short4v*)(vp + base + (vt0 + 0) * 64 + vd0);
    vreg1 = *(const short4v*)(vp + base + (vt0 + 1) * 64 + vd0);
    vreg2 = *(const short4v*)(vp + base + (vt0 + 2) * 64 + vd0);
    vreg3 = *(const short4v*)(vp + base + (vt0 + 3) * 64 + vd0);

    for (int kt = 0; kt < nkt; ++kt) {
        __syncthreads();
        *(bf16x8*)((char*)Ks + r0 * 128 + ((c0 * 2) ^ ((r0 & 7) << 4))) = kreg0;
        *(bf16x8*)((char*)Ks + r1 * 128 + ((c0 * 2) ^ ((r1 & 7) << 4))) = kreg1;
#pragma unroll
        for (int i = 0; i < 4; ++i) {
            short4v w; w[0] = vreg0[i]; w[1] = vreg1[i]; w[2] = vreg2[i]; w[3] = vreg3[i];
            int d = vd0 + i;
            int swz = ((d & 7) ^ (d >> 3)) << 4;
            *(short4v*)((char*)Vt + d * 256 + ((vt0 * 2) ^ swz)) = w;
        }
        if (kt + 1 < nkt) {
            const short* kp2 = kp + base + (kt + 1) * 8192;
            const short* vp2 = vp + base + (kt + 1) * 8192;
            kreg0 = *(const bf16x8*)(kp2 + r0 * 64 + c0);
            kreg1 = *(const bf16x8*)(kp2 + r1 * 64 + c0);
            vreg0 = *(const short4v*)(vp2 + (vt0 + 0) * 64 + vd0);
            vreg1 = *(const short4v*)(vp2 + (vt0 + 1) * 64 + vd0);
            vreg2 = *(const short4v*)(vp2 + (vt0 + 2) * 64 + vd0);
            vreg3 = *(const short4v*)(vp2 + (vt0 + 3) * 64 + vd0);
        }
        __syncthreads();

        const bool diag = (kt == nkt - 1);
        const int nlim = diag ? (wid + 1) : 8;

        f32x4 s[8];
        __builtin_amdgcn_s_setprio(1);
#pragma unroll
        for (int n = 0; n < 8; ++n) {
            s[n] = fz;
            if (n < nlim) {
                int row = n * 16 + c;
                int swz = (row & 7) << 4;
                bf16x8 kf0 = *(const bf16x8*)((const char*)Ks + row * 128 + ((g * 16) ^ swz));
                bf16x8 kf1 = *(const bf16x8*)((const char*)Ks + row * 128 + ((64 + g * 16) ^ swz));
                s[n] = __builtin_amdgcn_mfma_f32_16x16x32_bf16(qf0, kf0, s[n], 0, 0, 0);
                s[n] = __builtin_amdgcn_mfma_f32_16x16x32_bf16(qf1, kf1, s[n], 0, 0, 0);
            }
        }
        __builtin_amdgcn_s_setprio(0);

        // Q was pre-scaled: s already = score * log2(e)/8
        const int qg0 = q0 + wid * 16 + g * 4;
        float pm[4];
#pragma unroll
        for (int i = 0; i < 4; ++i) pm[i] = -1e30f;
        if (diag) {
#pragma unroll
            for (int n = 0; n < 8; ++n) {
                int kg = kt * 128 + n * 16 + c;
#pragma unroll
                for (int i = 0; i < 4; ++i) {
                    float vv = s[n][i];
                    vv = (kg <= qg0 + i) ? vv : -1e30f;
                    s[n][i] = vv;
                    pm[i] = fmaxf(pm[i], vv);
                }
            }
        } else {
#pragma unroll
            for (int n = 0; n < 8; ++n)
#pragma unroll
                for (int i = 0; i < 4; ++i)
                    pm[i] = fmaxf(pm[i], s[n][i]);
        }
#pragma unroll
        for (int off = 1; off < 16; off <<= 1)
#pragma unroll
            for (int i = 0; i < 4; ++i)
                pm[i] = fmaxf(pm[i], __shfl_xor(pm[i], off));

        // online softmax update with defer-max (T13); lsum deferred reduce
        int need = 0;
#pragma unroll
        for (int i = 0; i < 4; ++i) need |= (pm[i] > mrow[i] + 8.f) ? 1 : 0;
        if (__any(need)) {
#pragma unroll
            for (int i = 0; i < 4; ++i) {
                float mnew = fmaxf(mrow[i], pm[i]);
                float corr = exp2f(mrow[i] - mnew);
                mrow[i] = mnew;
                lsum[i] *= corr;
#pragma unroll
                for (int n = 0; n < 4; ++n) accO[n][i] *= corr;
            }
        }
#pragma unroll
        for (int n = 0; n < 8; ++n)
#pragma unroll
            for (int i = 0; i < 4; ++i) {
                float pv = exp2f(s[n][i] - mrow[i]);
                s[n][i] = pv;
                lsum[i] += pv;
            }

        // ---- PV in two 64-key halves through the small per-wave Ps buffer ----
#pragma unroll
        for (int hf = 0; hf < 2; ++hf) {
            asm volatile("s_waitcnt lgkmcnt(0)" ::: "memory");
            __builtin_amdgcn_sched_barrier(0);
#pragma unroll
            for (int n4 = 0; n4 < 4; ++n4) {
                int tl = n4 * 16 + c;
#pragma unroll
                for (int i = 0; i < 4; ++i) {
                    int q = g * 4 + i;
                    *(short*)((char*)&Ps[wid][0] + q * 128 + ((tl * 2) ^ ((q & 7) << 4))) =
                        f2bf(s[hf * 4 + n4][i]);
                }
            }
            asm volatile("s_waitcnt lgkmcnt(0)" ::: "memory");
            __builtin_amdgcn_sched_barrier(0);
#pragma unroll
            for (int ksl = 0; ksl < 2; ++ksl) {
                const int ks = hf * 2 + ksl;
                bf16x8 paf = *(const bf16x8*)((const char*)&Ps[wid][0] +
                                              c * 128 + ((ksl * 64 + g * 16) ^ ((c & 7) << 4)));
                __builtin_amdgcn_s_setprio(1);
#pragma unroll
                for (int n = 0; n < 4; ++n) {
                    int d = n * 16 + c;
                    int swz = ((d & 7) ^ (d >> 3)) << 4;
                    bf16x8 vf = *(const bf16x8*)((const char*)Vt + d * 256 + ((ks * 64 + g * 16) ^ swz));
                    accO[n] = __builtin_amdgcn_mfma_f32_16x16x32_bf16(paf, vf, accO[n], 0, 0, 0);
                }
                __builtin_amdgcn_s_setprio(0);
            }
        }
    }

    // epilogue: reduce deferred row-sums, normalize, store
    float lrow[4];
#pragma unroll
    for (int i = 0; i < 4; ++i) lrow[i] = lsum[i];
#pragma unroll
    for (int off = 1; off < 16; off <<= 1)
#pragma unroll
        for (int i = 0; i < 4; ++i)
            lrow[i] += __shfl_xor(lrow[i], off);
    float inv[4];
#pragma unroll
    for (int i = 0; i < 4; ++i) inv[i] = __builtin_amdgcn_rcpf(lrow[i]);
#pragma unroll
    for (int n = 0; n < 4; ++n)
#pragma unroll
        for (int i = 0; i < 4; ++i) {
            int t = q0 + wid * 16 + g * 4 + i;
            float o = accO[n][i] * inv[i];
            ao[(b * 1024 + t) * 1024 + h * 64 + n * 16 + c] = f2bf(o);
        }
}

extern "C" void kernel_launch(void* const* d_in, const int* in_sizes, int n_in,
                              void* d_out, int out_size, void* d_ws, size_t ws_size,
                              hipStream_t stream) {
    const float* x  = (const float*)d_in[0];
    const float* Wq = (const float*)d_in[1];
    const float* Wk = (const float*)d_in[2];
    const float* Wv = (const float*)d_in[3];
    const float* Wo = (const float*)d_in[4];
    const float* bo = (const float*)d_in[5];
    const float* W1 = (const float*)d_in[6];
    const float* b1 = (const float*)d_in[7];

    char* ws = (char*)d_ws;
    short* xb    = (short*)(ws + 0);          // 16.78 MB  [8192][1024] bf16
    short* wallT = (short*)(ws + 16777216);   // 10.49 MB: Wq^T|Wk^T|Wv^T | Wo plain | W1^T
    short* qb    = (short*)(ws + 27262976);   // 3 x 16.78 MB: q,k,v [B*H][T][64] bf16
    short* kb    = qb + 8388608;
    short* vb    = qb + 16777216;
    short* ao    = xb;                        // reuse
    short* wqkvT = wallT;
    short* woBF  = wallT + 3145728;
    short* w1T   = wallT + 4194304;
    short* wcombT= wqkvT;                     // reuse wqkvT region AFTER gemm<0>
    float* bcomb = (float*)(ws + 16777216 + 2097152);

    cvt_x_kernel<<<4096, 256, 0, stream>>>(x, xb);
    wtrans5_kernel<<<dim3(16, 16, 5), 256, 0, stream>>>(Wq, Wk, Wv, Wo, W1, wallT);

    gemm_bt<0><<<dim3(64, 24), 256, 0, stream>>>(xb, wqkvT, nullptr, (void*)qb);
    gemm64_bt<<<dim3(16, 16), 256, 0, stream>>>(w1T, woBF, wcombT);
    bcomb_kernel<<<64, 256, 0, stream>>>(bo, W1, b1, bcomb);
    attn_kernel<<<dim3(8, 128), 512, 0, stream>>>(qb, kb, vb, ao);
    gemm_bt<2><<<dim3(64, 8), 256, 0, stream>>>(ao, wcombT, bcomb, d_out);
}

// Round 16
// 167.209 us; speedup vs baseline: 1.3324x; 1.3324x over previous
//
#include <hip/hip_runtime.h>

typedef __bf16 bf16x8 __attribute__((ext_vector_type(8)));
typedef float f32x4 __attribute__((ext_vector_type(4)));
typedef short short4v __attribute__((ext_vector_type(4)));
typedef short short8v __attribute__((ext_vector_type(8)));

#define DEVI static __device__ __forceinline__

// fp32 -> bf16 bits via hardware cvt (RTNE; pairs fold to v_cvt_pk_bf16_f32)
DEVI short f2bf(float f) {
    union { __bf16 b; short s; } u;
    u.b = (__bf16)f;
    return u.s;
}

// async global -> LDS, 16B per lane (dest linear: wave-uniform base + lane*16)
DEVI void gld16(const void* g, void* l) {
    __builtin_amdgcn_global_load_lds(
        (const __attribute__((address_space(1))) unsigned int*)g,
        (__attribute__((address_space(3))) unsigned int*)l, 16, 0, 0);
}

// ---------------- x fp32 -> bf16 ----------------
__global__ __launch_bounds__(256) void cvt_x_kernel(const float* __restrict__ x,
                                                    short* __restrict__ xb) {
    int i = (blockIdx.x * 256 + threadIdx.x) * 8;
    f32x4 a = *(const f32x4*)(x + i);
    f32x4 b = *(const f32x4*)(x + i + 4);
    short8v o;
    o[0]=f2bf(a[0]); o[1]=f2bf(a[1]); o[2]=f2bf(a[2]); o[3]=f2bf(a[3]);
    o[4]=f2bf(b[0]); o[5]=f2bf(b[1]); o[6]=f2bf(b[2]); o[7]=f2bf(b[3]);
    *(short8v*)(xb + i) = o;
}

// ------------- weights fp32 -> bf16, fused. z=0,1,2: Wq,Wk,Wv transposed [N][K];
// z=3: Wo PLAIN [K][N] bf16; z=4: W1 transposed.
__global__ __launch_bounds__(256) void wtrans5_kernel(const float* __restrict__ w0,
                                                      const float* __restrict__ w1,
                                                      const float* __restrict__ w2,
                                                      const float* __restrict__ w3,
                                                      const float* __restrict__ w4,
                                                      short* __restrict__ dst) {
    const float* w;
    switch (blockIdx.z) {
        case 0: w = w0; break;
        case 1: w = w1; break;
        case 2: w = w2; break;
        case 3: w = w3; break;
        default: w = w4; break;
    }
    short* wt = dst + (size_t)blockIdx.z * 1048576;
    __shared__ float t[64][68];
    const int tid = threadIdx.x;
    const int k0 = blockIdx.x * 64, n0 = blockIdx.y * 64;
#pragma unroll
    for (int it = 0; it < 4; ++it) {
        int r = (tid >> 4) + it * 16;
        int cc = (tid & 15) * 4;
        f32x4 vv = *(const f32x4*)(w + (k0 + r) * 1024 + n0 + cc);
        *(f32x4*)&t[r][cc] = vv;
    }
    __syncthreads();
    if (blockIdx.z == 3) {
#pragma unroll
        for (int it = 0; it < 4; ++it) {
            int r = (tid >> 4) + it * 16;
            int cc = (tid & 15) * 4;
            short4v o;
            o[0] = f2bf(t[r][cc + 0]);
            o[1] = f2bf(t[r][cc + 1]);
            o[2] = f2bf(t[r][cc + 2]);
            o[3] = f2bf(t[r][cc + 3]);
            *(short4v*)(wt + (k0 + r) * 1024 + n0 + cc) = o;
        }
    } else {
#pragma unroll
        for (int it = 0; it < 4; ++it) {
            int n = (tid >> 4) + it * 16;
            int kc = (tid & 15) * 4;
            short4v o;
            o[0] = f2bf(t[kc + 0][n]);
            o[1] = f2bf(t[kc + 1][n]);
            o[2] = f2bf(t[kc + 2][n]);
            o[3] = f2bf(t[kc + 3][n]);
            *(short4v*)(wt + (n0 + n) * 1024 + k0 + kc) = o;
        }
    }
}

// ------- bcomb[n] = b1[n] + sum_j bo[j]*W1[j][n], parallel: 64 blocks x 16 n -------
__global__ __launch_bounds__(256) void bcomb_kernel(const float* __restrict__ bo,
                                                    const float* __restrict__ W1,
                                                    const float* __restrict__ b1,
                                                    float* __restrict__ out) {
    __shared__ f32x4 red[64][4];
    const int tid = threadIdx.x;
    const int jg = tid >> 2;
    const int nq = tid & 3;
    const int n = blockIdx.x * 16 + nq * 4;
    f32x4 acc = {0.f, 0.f, 0.f, 0.f};
#pragma unroll 4
    for (int jj = 0; jj < 16; ++jj) {
        int j = jg * 16 + jj;
        float s = bo[j];
        f32x4 w = *(const f32x4*)(W1 + j * 1024 + n);
        acc[0] += s * w[0]; acc[1] += s * w[1]; acc[2] += s * w[2]; acc[3] += s * w[3];
    }
    red[jg][nq] = acc;
    __syncthreads();
#pragma unroll
    for (int s = 32; s >= 1; s >>= 1) {
        if (jg < s) {
            f32x4 a = red[jg][nq], b2 = red[jg + s][nq];
            a[0] += b2[0]; a[1] += b2[1]; a[2] += b2[2]; a[3] += b2[3];
            red[jg][nq] = a;
        }
        __syncthreads();
    }
    if (jg == 0) {
        f32x4 r = red[0][nq];
        f32x4 bb = *(const f32x4*)(b1 + n);
        r[0] += bb[0]; r[1] += bb[1]; r[2] += bb[2]; r[3] += bb[3];
        *(f32x4*)(out + n) = r;
    }
}

// ------- 64x64-tile GEMM for the small 1024^3 composite (256 blocks, full chip) -------
__global__ __launch_bounds__(256, 2) void gemm64_bt(const short* __restrict__ A,
                                                    const short* __restrict__ Bt,
                                                    short* __restrict__ outp) {
    __shared__ short As[64 * 64];
    __shared__ short Bs[64 * 64];
    const int tid = threadIdx.x;
    const int lane = tid & 63;
    const int wid = tid >> 6;
    const int g = lane >> 4, c = lane & 15;
    const int wr = wid >> 1, wc = wid & 1;
    const int m0 = blockIdx.x * 64, n0 = blockIdx.y * 64;

    const f32x4 fz = {0.f, 0.f, 0.f, 0.f};
    f32x4 acc[2][2];
#pragma unroll
    for (int m = 0; m < 2; ++m)
#pragma unroll
        for (int n = 0; n < 2; ++n) acc[m][n] = fz;

    for (int kt = 0; kt < 16; ++kt) {
        const int k0 = kt * 64;
        __syncthreads();
#pragma unroll
        for (int st = 0; st < 2; ++st) {
            int ci = st * 256 + tid;
            int r = ci >> 3;
            int cc = ((ci & 7) ^ (r & 7)) << 3;
            gld16(A + (m0 + r) * 1024 + k0 + cc, (char*)As + ci * 16);
            gld16(Bt + (n0 + r) * 1024 + k0 + cc, (char*)Bs + ci * 16);
        }
        __syncthreads();
#pragma unroll
        for (int kk = 0; kk < 2; ++kk) {
            bf16x8 af[2], bfr[2];
#pragma unroll
            for (int m = 0; m < 2; ++m) {
                int row = wr * 32 + m * 16 + c;
                af[m] = *(const bf16x8*)((const char*)As + row * 128 + ((kk * 64 + g * 16) ^ ((row & 7) << 4)));
            }
#pragma unroll
            for (int n = 0; n < 2; ++n) {
                int row = wc * 32 + n * 16 + c;
                bfr[n] = *(const bf16x8*)((const char*)Bs + row * 128 + ((kk * 64 + g * 16) ^ ((row & 7) << 4)));
            }
#pragma unroll
            for (int m = 0; m < 2; ++m)
#pragma unroll
                for (int n = 0; n < 2; ++n)
                    acc[m][n] = __builtin_amdgcn_mfma_f32_16x16x32_bf16(af[m], bfr[n], acc[m][n], 0, 0, 0);
        }
    }

#pragma unroll
    for (int n = 0; n < 2; ++n) {
        const int col = n0 + wc * 32 + n * 16 + c;
#pragma unroll
        for (int m = 0; m < 2; ++m) {
            const int row0 = m0 + wr * 32 + m * 16 + g * 4;
#pragma unroll
            for (int i = 0; i < 4; ++i)
                outp[(row0 + i) * 1024 + col] = f2bf(acc[m][n][i]);
        }
    }
}

// ---------------- GEMM (m97 structure + T2 swizzle): C = A @ Bt^T ----------------
// MODE 0: scatter bf16 to q/k/v; q pre-scaled by 1/8*log2(e)
// MODE 2: fp32 out = relu(acc + bias)
template<int MODE>
__global__ __launch_bounds__(256, 2) void gemm_bt(const short* __restrict__ A,
                                                  const short* __restrict__ Bt,
                                                  const float* __restrict__ bias,
                                                  void* __restrict__ outp) {
    __shared__ short As[128 * 64];
    __shared__ short Bs[128 * 64];
    const int tid = threadIdx.x;
    const int lane = tid & 63;
    const int wid = tid >> 6;
    const int g = lane >> 4, c = lane & 15;
    const int wr = wid >> 1, wc = wid & 1;
    const int m0 = blockIdx.x * 128, n0 = blockIdx.y * 128;

    const f32x4 fz = {0.f, 0.f, 0.f, 0.f};
    f32x4 acc[4][4];
#pragma unroll
    for (int m = 0; m < 4; ++m)
#pragma unroll
        for (int n = 0; n < 4; ++n) acc[m][n] = fz;

    for (int kt = 0; kt < 16; ++kt) {
        const int k0 = kt * 64;
        __syncthreads();
#pragma unroll
        for (int st = 0; st < 4; ++st) {
            int ci = st * 256 + tid;
            int r = ci >> 3;
            int cc = ((ci & 7) ^ (r & 7)) << 3;
            gld16(A + (m0 + r) * 1024 + k0 + cc, (char*)As + ci * 16);
            gld16(Bt + (n0 + r) * 1024 + k0 + cc, (char*)Bs + ci * 16);
        }
        __syncthreads();
#pragma unroll
        for (int kk = 0; kk < 2; ++kk) {
            bf16x8 af[4], bfr[4];
#pragma unroll
            for (int m = 0; m < 4; ++m) {
                int row = wr * 64 + m * 16 + c;
                af[m] = *(const bf16x8*)((const char*)As + row * 128 + ((kk * 64 + g * 16) ^ ((row & 7) << 4)));
            }
#pragma unroll
            for (int n = 0; n < 4; ++n) {
                int row = wc * 64 + n * 16 + c;
                bfr[n] = *(const bf16x8*)((const char*)Bs + row * 128 + ((kk * 64 + g * 16) ^ ((row & 7) << 4)));
            }
#pragma unroll
            for (int m = 0; m < 4; ++m)
#pragma unroll
                for (int n = 0; n < 4; ++n)
                    acc[m][n] = __builtin_amdgcn_mfma_f32_16x16x32_bf16(af[m], bfr[n], acc[m][n], 0, 0, 0);
        }
    }

#pragma unroll
    for (int n = 0; n < 4; ++n) {
        const int col = n0 + wc * 64 + n * 16 + c;
        float bv = 0.f;
        if (MODE == 2) bv = bias[col];
#pragma unroll
        for (int m = 0; m < 4; ++m) {
            const int row0 = m0 + wr * 64 + m * 16 + g * 4;
#pragma unroll
            for (int i = 0; i < 4; ++i) {
                const int row = row0 + i;
                float val = acc[m][n][i];
                if (MODE == 0) {
                    short* qkv = (short*)outp;
                    int which = col >> 10;
                    int hc = col & 1023;
                    if (which == 0) val *= 0.18033688011112042f;
                    int dst = which * 8388608 +
                              (((row >> 10) * 16 + (hc >> 6)) * 1024 + (row & 1023)) * 64 + (hc & 63);
                    qkv[dst] = f2bf(val);
                } else {
                    ((float*)outp)[row * 1024 + col] = fmaxf(val + bv, 0.f);
                }
            }
        }
    }
}

// ---------------- causal flash attention v3.2 (Q pre-scaled upstream) ----------------
// grid (4, B*H), 512 threads / 8 waves; q-tile pairing {bx,7-bx} (9 tiles/block,
// all blocks equal length -> no scheduling tail). Reg-prefetch (T14), diag-only
// masking, defer-max (T13), deferred row-sum, setprio (T5).
__global__ __launch_bounds__(512, 2) void attn_kernel(const short* __restrict__ qp,
                                                      const short* __restrict__ kp,
                                                      const short* __restrict__ vp,
                                                      short* __restrict__ ao) {
    __shared__ short Ks[128 * 64];    // row t: 128B rows, swz ((r&7)<<4)
    __shared__ short Vt[64 * 128];    // row d: 256B rows, swz (((d&7)^(d>>3))<<4)
    __shared__ short Ps[8][16 * 64];  // per-wave P half [q][64], 128B rows, swz ((q&7)<<4)
    const int tid = threadIdx.x;
    const int lane = tid & 63;
    const int wid = tid >> 6;
    const int g = lane >> 4, c = lane & 15;
    const int bh = blockIdx.y;
    const int base = bh * 65536;  // 1024*64
    const int b = bh >> 4, h = bh & 15;

    const int r0 = tid >> 3, c0 = (tid & 7) << 3;
    const int r1 = 64 + r0;
    const int vt0 = (tid >> 4) * 4;   // 0..124
    const int vd0 = (tid & 15) * 4;   // 0..60

    const f32x4 fz = {0.f, 0.f, 0.f, 0.f};

    bf16x8 kreg0, kreg1;
    short4v vreg0, vreg1, vreg2, vreg3;

#pragma unroll 1
    for (int ph = 0; ph < 2; ++ph) {
        const int qt = ph ? (7 - blockIdx.x) : blockIdx.x;
        const int q0 = qt * 128;
        const int nkt = qt + 1;

        const int qrow = q0 + wid * 16 + c;
        bf16x8 qf0 = *(const bf16x8*)(qp + base + qrow * 64 + g * 8);
        bf16x8 qf1 = *(const bf16x8*)(qp + base + qrow * 64 + 32 + g * 8);

        f32x4 accO[4];
#pragma unroll
        for (int n = 0; n < 4; ++n) accO[n] = fz;
        float mrow[4], lsum[4];
#pragma unroll
        for (int i = 0; i < 4; ++i) { mrow[i] = -1e30f; lsum[i] = 0.f; }

        kreg0 = *(const bf16x8*)(kp + base + r0 * 64 + c0);
        kreg1 = *(const bf16x8*)(kp + base + r1 * 64 + c0);
        vreg0 = *(const short4v*)(vp + base + (vt0 + 0) * 64 + vd0);
        vreg1 = *(const short4v*)(vp + base + (vt0 + 1) * 64 + vd0);
        vreg2 = *(const short4v*)(vp + base + (vt0 + 2) * 64 + vd0);
        vreg3 = *(const short4v*)(vp + base + (vt0 + 3) * 64 + vd0);

        for (int kt = 0; kt < nkt; ++kt) {
            __syncthreads();
            *(bf16x8*)((char*)Ks + r0 * 128 + ((c0 * 2) ^ ((r0 & 7) << 4))) = kreg0;
            *(bf16x8*)((char*)Ks + r1 * 128 + ((c0 * 2) ^ ((r1 & 7) << 4))) = kreg1;
#pragma unroll
            for (int i = 0; i < 4; ++i) {
                short4v w; w[0] = vreg0[i]; w[1] = vreg1[i]; w[2] = vreg2[i]; w[3] = vreg3[i];
                int d = vd0 + i;
                int swz = ((d & 7) ^ (d >> 3)) << 4;
                *(short4v*)((char*)Vt + d * 256 + ((vt0 * 2) ^ swz)) = w;
            }
            if (kt + 1 < nkt) {
                const short* kp2 = kp + base + (kt + 1) * 8192;
                const short* vp2 = vp + base + (kt + 1) * 8192;
                kreg0 = *(const bf16x8*)(kp2 + r0 * 64 + c0);
                kreg1 = *(const bf16x8*)(kp2 + r1 * 64 + c0);
                vreg0 = *(const short4v*)(vp2 + (vt0 + 0) * 64 + vd0);
                vreg1 = *(const short4v*)(vp2 + (vt0 + 1) * 64 + vd0);
                vreg2 = *(const short4v*)(vp2 + (vt0 + 2) * 64 + vd0);
                vreg3 = *(const short4v*)(vp2 + (vt0 + 3) * 64 + vd0);
            }
            __syncthreads();

            const bool diag = (kt == nkt - 1);
            const int nlim = diag ? (wid + 1) : 8;

            f32x4 s[8];
            __builtin_amdgcn_s_setprio(1);
#pragma unroll
            for (int n = 0; n < 8; ++n) {
                s[n] = fz;
                if (n < nlim) {
                    int row = n * 16 + c;
                    int swz = (row & 7) << 4;
                    bf16x8 kf0 = *(const bf16x8*)((const char*)Ks + row * 128 + ((g * 16) ^ swz));
                    bf16x8 kf1 = *(const bf16x8*)((const char*)Ks + row * 128 + ((64 + g * 16) ^ swz));
                    s[n] = __builtin_amdgcn_mfma_f32_16x16x32_bf16(qf0, kf0, s[n], 0, 0, 0);
                    s[n] = __builtin_amdgcn_mfma_f32_16x16x32_bf16(qf1, kf1, s[n], 0, 0, 0);
                }
            }
            __builtin_amdgcn_s_setprio(0);

            // Q was pre-scaled: s already = score * log2(e)/8
            const int qg0 = q0 + wid * 16 + g * 4;
            float pm[4];
#pragma unroll
            for (int i = 0; i < 4; ++i) pm[i] = -1e30f;
            if (diag) {
#pragma unroll
                for (int n = 0; n < 8; ++n) {
                    int kg = kt * 128 + n * 16 + c;
#pragma unroll
                    for (int i = 0; i < 4; ++i) {
                        float vv = s[n][i];
                        vv = (kg <= qg0 + i) ? vv : -1e30f;
                        s[n][i] = vv;
                        pm[i] = fmaxf(pm[i], vv);
                    }
                }
            } else {
#pragma unroll
                for (int n = 0; n < 8; ++n)
#pragma unroll
                    for (int i = 0; i < 4; ++i)
                        pm[i] = fmaxf(pm[i], s[n][i]);
            }
#pragma unroll
            for (int off = 1; off < 16; off <<= 1)
#pragma unroll
                for (int i = 0; i < 4; ++i)
                    pm[i] = fmaxf(pm[i], __shfl_xor(pm[i], off));

            // online softmax update with defer-max (T13); lsum deferred reduce
            int need = 0;
#pragma unroll
            for (int i = 0; i < 4; ++i) need |= (pm[i] > mrow[i] + 8.f) ? 1 : 0;
            if (__any(need)) {
#pragma unroll
                for (int i = 0; i < 4; ++i) {
                    float mnew = fmaxf(mrow[i], pm[i]);
                    float corr = exp2f(mrow[i] - mnew);
                    mrow[i] = mnew;
                    lsum[i] *= corr;
#pragma unroll
                    for (int n = 0; n < 4; ++n) accO[n][i] *= corr;
                }
            }
#pragma unroll
            for (int n = 0; n < 8; ++n)
#pragma unroll
                for (int i = 0; i < 4; ++i) {
                    float pv = exp2f(s[n][i] - mrow[i]);
                    s[n][i] = pv;
                    lsum[i] += pv;
                }

            // ---- PV in two 64-key halves through the small per-wave Ps buffer ----
#pragma unroll
            for (int hf = 0; hf < 2; ++hf) {
                asm volatile("s_waitcnt lgkmcnt(0)" ::: "memory");
                __builtin_amdgcn_sched_barrier(0);
#pragma unroll
                for (int n4 = 0; n4 < 4; ++n4) {
                    int tl = n4 * 16 + c;
#pragma unroll
                    for (int i = 0; i < 4; ++i) {
                        int q = g * 4 + i;
                        *(short*)((char*)&Ps[wid][0] + q * 128 + ((tl * 2) ^ ((q & 7) << 4))) =
                            f2bf(s[hf * 4 + n4][i]);
                    }
                }
                asm volatile("s_waitcnt lgkmcnt(0)" ::: "memory");
                __builtin_amdgcn_sched_barrier(0);
#pragma unroll
                for (int ksl = 0; ksl < 2; ++ksl) {
                    const int ks = hf * 2 + ksl;
                    bf16x8 paf = *(const bf16x8*)((const char*)&Ps[wid][0] +
                                                  c * 128 + ((ksl * 64 + g * 16) ^ ((c & 7) << 4)));
                    __builtin_amdgcn_s_setprio(1);
#pragma unroll
                    for (int n = 0; n < 4; ++n) {
                        int d = n * 16 + c;
                        int swz = ((d & 7) ^ (d >> 3)) << 4;
                        bf16x8 vf = *(const bf16x8*)((const char*)Vt + d * 256 + ((ks * 64 + g * 16) ^ swz));
                        accO[n] = __builtin_amdgcn_mfma_f32_16x16x32_bf16(paf, vf, accO[n], 0, 0, 0);
                    }
                    __builtin_amdgcn_s_setprio(0);
                }
            }
        }

        // epilogue: reduce deferred row-sums, normalize, store
        float lrow[4];
#pragma unroll
        for (int i = 0; i < 4; ++i) lrow[i] = lsum[i];
#pragma unroll
        for (int off = 1; off < 16; off <<= 1)
#pragma unroll
            for (int i = 0; i < 4; ++i)
                lrow[i] += __shfl_xor(lrow[i], off);
        float inv[4];
#pragma unroll
        for (int i = 0; i < 4; ++i) inv[i] = __builtin_amdgcn_rcpf(lrow[i]);
#pragma unroll
        for (int n = 0; n < 4; ++n)
#pragma unroll
            for (int i = 0; i < 4; ++i) {
                int t = q0 + wid * 16 + g * 4 + i;
                float o = accO[n][i] * inv[i];
                ao[(b * 1024 + t) * 1024 + h * 64 + n * 16 + c] = f2bf(o);
            }
    }
}

extern "C" void kernel_launch(void* const* d_in, const int* in_sizes, int n_in,
                              void* d_out, int out_size, void* d_ws, size_t ws_size,
                              hipStream_t stream) {
    const float* x  = (const float*)d_in[0];
    const float* Wq = (const float*)d_in[1];
    const float* Wk = (const float*)d_in[2];
    const float* Wv = (const float*)d_in[3];
    const float* Wo = (const float*)d_in[4];
    const float* bo = (const float*)d_in[5];
    const float* W1 = (const float*)d_in[6];
    const float* b1 = (const float*)d_in[7];

    char* ws = (char*)d_ws;
    short* xb    = (short*)(ws + 0);          // 16.78 MB  [8192][1024] bf16
    short* wallT = (short*)(ws + 16777216);   // 10.49 MB: Wq^T|Wk^T|Wv^T | Wo plain | W1^T
    short* qb    = (short*)(ws + 27262976);   // 3 x 16.78 MB: q,k,v [B*H][T][64] bf16
    short* kb    = qb + 8388608;
    short* vb    = qb + 16777216;
    short* ao    = xb;                        // reuse
    short* wqkvT = wallT;
    short* woBF  = wallT + 3145728;
    short* w1T   = wallT + 4194304;
    short* wcombT= wqkvT;                     // reuse wqkvT region AFTER gemm<0>
    float* bcomb = (float*)(ws + 16777216 + 2097152);

    cvt_x_kernel<<<4096, 256, 0, stream>>>(x, xb);
    wtrans5_kernel<<<dim3(16, 16, 5), 256, 0, stream>>>(Wq, Wk, Wv, Wo, W1, wallT);

    gemm_bt<0><<<dim3(64, 24), 256, 0, stream>>>(xb, wqkvT, nullptr, (void*)qb);
    gemm64_bt<<<dim3(16, 16), 256, 0, stream>>>(w1T, woBF, wcombT);
    bcomb_kernel<<<64, 256, 0, stream>>>(bo, W1, b1, bcomb);
    attn_kernel<<<dim3(4, 128), 512, 0, stream>>>(qb, kb, vb, ao);
    gemm_bt<2><<<dim3(64, 8), 256, 0, stream>>>(ao, wcombT, bcomb, d_out);
}